// Round 1
// baseline (1548.389 us; speedup 1.0000x reference)
//
#include <hip/hip_runtime.h>

// FP16(pulse bits, 16 floats of 0/1) -> FP8 E4M3 (pulse bits, 8 floats of 0/1).
// Memory-bound target: 1.074 GB in + 0.537 GB out per call, HBM floor ~256 us.
//
// Layout (unchanged from prior best): one thread = one uint4 (quarter item);
// lanes 4k..4k+3 hold parts 0..3 of item k. A 2-step intra-quad butterfly
// assembles the full 16-bit word in every lane, each lane converts (redundant
// x4 -- VALU is free), and each lane stores its uint2 slice of the output.
// Input uint4 index == output uint2 index == stream index: both streams
// perfectly lane-contiguous (16 B/lane load, 8 B/lane store).
//
// This revision attacks the issue/latency bottleneck (prev: 1437 us = 18% of
// achievable HBM BW, far off the ~256 us floor):
//  1. __shfl_xor -> DPP quad_perm (0xB1 = xor1, 0x4E = xor2). __shfl_xor
//     lowers to ds_bpermute_b32 + s_waitcnt lgkmcnt(0): two dependent LDS
//     round-trips per 24 B of traffic. quad_perm is a 1-cycle VALU op.
//  2. Grid-stride with x4 unroll: 4 independent 16 B loads in flight per
//     thread instead of 1 load / 1 store total (MLP, not just TLP).
//  3. 2048 blocks (8 blocks/CU x 4 waves = full residency) instead of 262k
//     tiny workgroups.
//  4. Non-temporal load/store: pure streaming, zero reuse.

typedef unsigned int u32;
typedef u32 u32x4 __attribute__((ext_vector_type(4)));
typedef u32 u32x2 __attribute__((ext_vector_type(2)));

// quad_perm DPP: lane i of each 4-lane quad reads lane perm[i].
// xor-1: perm {1,0,3,2} -> ctrl 0xB1 ; xor-2: perm {2,3,0,1} -> ctrl 0x4E.
__device__ __forceinline__ u32 qperm_xor1(u32 x) {
    return (u32)__builtin_amdgcn_update_dpp(0, (int)x, 0xB1, 0xF, 0xF, true);
}
__device__ __forceinline__ u32 qperm_xor2(u32 x) {
    return (u32)__builtin_amdgcn_update_dpp(0, (int)x, 0x4E, 0xF, 0xF, true);
}

__device__ __forceinline__ u32x2 convert_quarter(u32x4 v, u32 p) {
    // pulse word (0.0f / 1.0f) -> bit via mantissa-implicit bit 23
    const u32 nib = ((((v.x) >> 23) & 1u) << 3) | ((((v.y) >> 23) & 1u) << 2) |
                    ((((v.z) >> 23) & 1u) << 1) |  (((v.w) >> 23) & 1u);

    // butterfly transpose within each 4-lane quad: all lanes end with word16
    const u32 o1   = qperm_xor1(nib);
    const u32 pair = (p & 1u) ? ((o1 << 4) | nib) : ((nib << 4) | o1);
    const u32 o2   = qperm_xor2(pair);
    const u32 word = (p & 2u) ? ((o2 << 8) | pair) : ((pair << 8) | o2);

    const u32 s = word >> 15;
    const u32 e = (word >> 10) & 31u;
    const u32 m = word & 1023u;

    // --- normal path: RNE(m >> 7), exponent bump on mantissa carry
    const u32 keep_n   = m >> 7;
    const u32 rbit_n   = (m >> 6) & 1u;
    const u32 sticky_n = (m & 63u) ? 1u : 0u;
    const u32 mant_r   = keep_n + (rbit_n & (sticky_n | (keep_n & 1u)));
    const u32 norm_e   = (e - 8u) + (mant_r >> 3);   // only selected when e >= 9
    const u32 norm_m   = mant_r & 7u;

    // --- subnormal path: RNE((1024 + m) >> clip(16-e, 8, 11))
    u32 k = 16u - e;
    k = k < 8u ? 8u : (k > 11u ? 11u : k);
    const u32 x        = 1024u + m;
    const u32 keep_s   = x >> k;
    const u32 rbit_s   = (x >> (k - 1u)) & 1u;
    const u32 sticky_s = (x & ((1u << (k - 1u)) - 1u)) ? 1u : 0u;
    const u32 m_sub    = keep_s + (rbit_s & (sticky_s | (keep_s & 1u)));
    const u32 sub_e    = m_sub >> 3;
    const u32 sub_m    = (m_sub >= 8u) ? 0u : m_sub;

    // --- branchless select (ovf | unf | subnormal | normal)
    const u32 out_e = (e > 22u) ? 15u : (e < 5u) ? 0u : (e <= 8u) ? sub_e : norm_e;
    const u32 out_m = (e > 22u) ? 6u  : (e < 5u) ? 0u : (e <= 8u) ? sub_m : norm_m;

    // output byte, MSB first: [S, e3, e2, e1, e0, m2, m1, m0]
    const u32 obyte = (s << 7) | (out_e << 3) | out_m;

    // lane p stores output bits (7-2p) and (6-2p) as two pulse words
    const u32 hi = (obyte >> (7u - 2u * p)) & 1u;
    const u32 lo = (obyte >> (6u - 2u * p)) & 1u;

    u32x2 o;
    o.x = (0u - hi) & 0x3F800000u;
    o.y = (0u - lo) & 0x3F800000u;
    return o;
}

__global__ __launch_bounds__(256) void fp16_to_fp8_pulse_kernel(
    const u32x4* __restrict__ in,   // one uint4 = 4 pulse bits (quarter item)
    u32x2* __restrict__ out,        // one uint2 = 2 output pulse words
    int n4)                          // total uint4 count = n_items * 4
{
    const int stride = (int)(gridDim.x * blockDim.x);
    const u32 p = (u32)(threadIdx.x & 3u);
    int g = (int)(blockIdx.x * blockDim.x + threadIdx.x);

    // Quad-uniformity of both loop guards: n4 % 4 == 0 (4 uint4s per item),
    // stride % 4 == 0, and quads have consecutive g with quad-base % 4 == 0,
    // so all 4 lanes of a quad take identical trip counts -> DPP is safe.

    // main chunks: 4 independent loads in flight per thread
    for (; g + 3 * stride < n4; g += 4 * stride) {
        const u32x4 v0 = __builtin_nontemporal_load(&in[g]);
        const u32x4 v1 = __builtin_nontemporal_load(&in[g + stride]);
        const u32x4 v2 = __builtin_nontemporal_load(&in[g + 2 * stride]);
        const u32x4 v3 = __builtin_nontemporal_load(&in[g + 3 * stride]);

        const u32x2 r0 = convert_quarter(v0, p);
        const u32x2 r1 = convert_quarter(v1, p);
        const u32x2 r2 = convert_quarter(v2, p);
        const u32x2 r3 = convert_quarter(v3, p);

        __builtin_nontemporal_store(r0, &out[g]);
        __builtin_nontemporal_store(r1, &out[g + stride]);
        __builtin_nontemporal_store(r2, &out[g + 2 * stride]);
        __builtin_nontemporal_store(r3, &out[g + 3 * stride]);
    }
    // remainder
    for (; g < n4; g += stride) {
        const u32x4 v = __builtin_nontemporal_load(&in[g]);
        __builtin_nontemporal_store(convert_quarter(v, p), &out[g]);
    }
}

extern "C" void kernel_launch(void* const* d_in, const int* in_sizes, int n_in,
                              void* d_out, int out_size, void* d_ws, size_t ws_size,
                              hipStream_t stream) {
    const u32x4* in = (const u32x4*)d_in[0];
    u32x2* out = (u32x2*)d_out;

    const int n4 = in_sizes[0] / 4;                // 67,108,864 uint4s
    const int block = 256;
    int grid = (n4 + block - 1) / block;
    if (grid > 2048) grid = 2048;                  // 8 blocks/CU, grid-stride

    fp16_to_fp8_pulse_kernel<<<grid, block, 0, stream>>>(in, out, n4);
}

// Round 2
// 1474.844 us; speedup vs baseline: 1.0499x; 1.0499x over previous
//
#include <hip/hip_runtime.h>

// FP16(pulse bits, 16 floats of 0/1) -> FP8 E4M3 (pulse bits, 8 floats of 0/1).
// Memory-bound: 1.074 GB in + 0.537 GB out per call, HBM floor ~256 us.
//
// Layout: one thread = one uint4 (quarter item); lanes 4k..4k+3 hold parts
// 0..3 of item k. A 2-step intra-quad DPP butterfly assembles the full 16-bit
// word in every lane, each lane converts (redundant x4 -- VALU is ~free), and
// each lane stores its uint2 slice of the output. Input uint4 index == output
// uint2 index: both streams perfectly lane-contiguous (16 B/lane load,
// 8 B/lane store).
//
// R1 lessons (counters): harness poison fills (4.3 GB @ 6.3 TB/s, ~680 us
// each) dominate the top-5; our kernel dispatch is < 677 us, so >= 871 us of
// dur_us is fixed harness overhead. R1's grid-stride (8 MB per-thread jumps)
// + non-temporal hints regressed ~110 us vs the fully-linear prior best.
// This round: back to fully-linear block-contiguous addressing (the 1437
// baseline's memory behavior), keep the DPP transpose (strictly cheaper than
// ds_bpermute + lgkmcnt drains), add x4 per-thread unroll for MLP
// (4 independent 16 B loads in flight instead of 1). No NT hints.

typedef unsigned int u32;
typedef u32 u32x4 __attribute__((ext_vector_type(4)));
typedef u32 u32x2 __attribute__((ext_vector_type(2)));

// quad_perm DPP: lane i of each 4-lane quad reads lane perm[i].
// xor-1: perm {1,0,3,2} -> ctrl 0xB1 ; xor-2: perm {2,3,0,1} -> ctrl 0x4E.
// 1-cycle VALU, no LDS pipe, no lgkmcnt waits.
__device__ __forceinline__ u32 qperm_xor1(u32 x) {
    return (u32)__builtin_amdgcn_update_dpp(0, (int)x, 0xB1, 0xF, 0xF, true);
}
__device__ __forceinline__ u32 qperm_xor2(u32 x) {
    return (u32)__builtin_amdgcn_update_dpp(0, (int)x, 0x4E, 0xF, 0xF, true);
}

__device__ __forceinline__ u32x2 convert_quarter(u32x4 v, u32 p) {
    // pulse word (0.0f / 1.0f) -> bit via the FP32 exponent LSB (bit 23)
    const u32 nib = ((((v.x) >> 23) & 1u) << 3) | ((((v.y) >> 23) & 1u) << 2) |
                    ((((v.z) >> 23) & 1u) << 1) |  (((v.w) >> 23) & 1u);

    // butterfly transpose within each 4-lane quad: all lanes end with word16
    const u32 o1   = qperm_xor1(nib);
    const u32 pair = (p & 1u) ? ((o1 << 4) | nib) : ((nib << 4) | o1);
    const u32 o2   = qperm_xor2(pair);
    const u32 word = (p & 2u) ? ((o2 << 8) | pair) : ((pair << 8) | o2);

    const u32 s = word >> 15;
    const u32 e = (word >> 10) & 31u;
    const u32 m = word & 1023u;

    // --- normal path: RNE(m >> 7), exponent bump on mantissa carry
    const u32 keep_n   = m >> 7;
    const u32 rbit_n   = (m >> 6) & 1u;
    const u32 sticky_n = (m & 63u) ? 1u : 0u;
    const u32 mant_r   = keep_n + (rbit_n & (sticky_n | (keep_n & 1u)));
    const u32 norm_e   = (e - 8u) + (mant_r >> 3);   // only selected when e >= 9
    const u32 norm_m   = mant_r & 7u;

    // --- subnormal path: RNE((1024 + m) >> clip(16-e, 8, 11))
    u32 k = 16u - e;
    k = k < 8u ? 8u : (k > 11u ? 11u : k);
    const u32 x        = 1024u + m;
    const u32 keep_s   = x >> k;
    const u32 rbit_s   = (x >> (k - 1u)) & 1u;
    const u32 sticky_s = (x & ((1u << (k - 1u)) - 1u)) ? 1u : 0u;
    const u32 m_sub    = keep_s + (rbit_s & (sticky_s | (keep_s & 1u)));
    const u32 sub_e    = m_sub >> 3;
    const u32 sub_m    = (m_sub >= 8u) ? 0u : m_sub;

    // --- branchless select (ovf | unf | subnormal | normal)
    const u32 out_e = (e > 22u) ? 15u : (e < 5u) ? 0u : (e <= 8u) ? sub_e : norm_e;
    const u32 out_m = (e > 22u) ? 6u  : (e < 5u) ? 0u : (e <= 8u) ? sub_m : norm_m;

    // output byte, MSB first: [S, e3, e2, e1, e0, m2, m1, m0]
    const u32 obyte = (s << 7) | (out_e << 3) | out_m;

    // lane p stores output bits (7-2p) and (6-2p) as two pulse words
    const u32 hi = (obyte >> (7u - 2u * p)) & 1u;
    const u32 lo = (obyte >> (6u - 2u * p)) & 1u;

    u32x2 o;
    o.x = (0u - hi) & 0x3F800000u;
    o.y = (0u - lo) & 0x3F800000u;
    return o;
}

#define UNROLL 4

__global__ __launch_bounds__(256) void fp16_to_fp8_pulse_kernel(
    const u32x4* __restrict__ in,   // one uint4 = 4 pulse bits (quarter item)
    u32x2* __restrict__ out,        // one uint2 = 2 output pulse words
    int n4)                          // total uint4 count = n_items * 4
{
    // Block-contiguous linear tile: block b owns uint4s [b*1024, b*1024+1024).
    // Thread t handles base, base+256, base+512, base+768 -> every vmem
    // instruction is perfectly lane-contiguous AND blocks tile the address
    // space linearly (no large per-thread strides).
    const u32 p = (u32)(threadIdx.x & 3u);
    const int base = (int)(blockIdx.x * (256u * UNROLL) + threadIdx.x);

    // Quad-uniformity of the guards: indices within a quad differ by <= 3 and
    // n4 % 4 == 0, so all 4 lanes of a quad take identical paths -> DPP safe.
    u32x4 v[UNROLL];
    #pragma unroll
    for (int k = 0; k < UNROLL; ++k) {
        const int idx = base + k * 256;
        if (idx < n4) v[k] = in[idx];     // 4 independent loads in flight
    }

    #pragma unroll
    for (int k = 0; k < UNROLL; ++k) {
        const int idx = base + k * 256;
        if (idx < n4) out[idx] = convert_quarter(v[k], p);
    }
}

extern "C" void kernel_launch(void* const* d_in, const int* in_sizes, int n_in,
                              void* d_out, int out_size, void* d_ws, size_t ws_size,
                              hipStream_t stream) {
    const u32x4* in = (const u32x4*)d_in[0];
    u32x2* out = (u32x2*)d_out;

    const int n4 = in_sizes[0] / 4;                      // 67,108,864 uint4s
    const int block = 256;
    const int grid = (n4 + block * UNROLL - 1) / (block * UNROLL);  // 65,536

    fp16_to_fp8_pulse_kernel<<<grid, block, 0, stream>>>(in, out, n4);
}

// Round 3
// 1440.212 us; speedup vs baseline: 1.0751x; 1.0240x over previous
//
#include <hip/hip_runtime.h>

// FP16(pulse bits, 16 floats of 0/1) -> FP8 E4M3 (pulse bits, 8 floats of 0/1).
// Memory-bound: 1.074 GB in + 0.537 GB out per call, kernel HBM floor ~270 us.
//
// Layout (= prior-session best, 1437 us wall): one thread = one uint4
// (quarter item); lanes 4k..4k+3 hold parts 0..3 of item k. A 2-step
// intra-quad butterfly assembles the full 16-bit fp16 word in every lane,
// each lane converts (redundant x4 -- VALU is ~40 us total, memory is ~500),
// and each lane stores its uint2 slice of the output. Input uint4 index ==
// output uint2 index == global thread id: both streams perfectly
// lane-contiguous (16 B/lane load, 8 B/lane store), fully linear tiling.
//
// Session A/B history:
//   R1 grid-stride 8MB jumps + NT hints:        1548 us  (regression)
//   R2 linear + x4 unroll + DPP:                1475 us
//   prior flat + ds_bpermute shfl:              1437 us
// Counters show the timed window carries >=790 us of harness poison-fill
// traffic (4.3 GB fills @ 6.2 TB/s dominate top-5; our dispatch < 681 us),
// so per-round wall deltas < ~30 us are fill-jitter. This round: flat
// structure (drop R2's unroll -- the only structural suspect) + DPP quad_perm
// (strictly fewer instructions than ds_bpermute + lgkmcnt(0) drains).

typedef unsigned int u32;
typedef u32 u32x4 __attribute__((ext_vector_type(4)));
typedef u32 u32x2 __attribute__((ext_vector_type(2)));

// quad_perm DPP: lane i of each 4-lane quad reads lane perm[i].
// xor-1: perm {1,0,3,2} -> ctrl 0xB1 ; xor-2: perm {2,3,0,1} -> ctrl 0x4E.
// 1-cycle VALU, no LDS pipe, no lgkmcnt waits. Safe here: all guards are
// quad-uniform (n4 % 4 == 0, quad indices differ by <= 3 below a multiple of 4).
__device__ __forceinline__ u32 qperm_xor1(u32 x) {
    return (u32)__builtin_amdgcn_update_dpp(0, (int)x, 0xB1, 0xF, 0xF, true);
}
__device__ __forceinline__ u32 qperm_xor2(u32 x) {
    return (u32)__builtin_amdgcn_update_dpp(0, (int)x, 0x4E, 0xF, 0xF, true);
}

__global__ __launch_bounds__(256) void fp16_to_fp8_pulse_kernel(
    const u32x4* __restrict__ in,   // one uint4 = 4 pulse bits (quarter item)
    u32x2* __restrict__ out,        // one uint2 = 2 output pulse words
    int n4)                          // total uint4 count = n_items * 4
{
    const int g = (int)(blockIdx.x * blockDim.x + threadIdx.x);
    if (g >= n4) return;

    const u32x4 v = in[g];
    const u32 p = (u32)(threadIdx.x & 3u);

    // pulse word (0.0f / 1.0f) -> bit via the FP32 exponent LSB (bit 23)
    const u32 nib = ((((v.x) >> 23) & 1u) << 3) | ((((v.y) >> 23) & 1u) << 2) |
                    ((((v.z) >> 23) & 1u) << 1) |  (((v.w) >> 23) & 1u);

    // butterfly transpose within each 4-lane quad: all lanes end with word16
    const u32 o1   = qperm_xor1(nib);
    const u32 pair = (p & 1u) ? ((o1 << 4) | nib) : ((nib << 4) | o1);
    const u32 o2   = qperm_xor2(pair);
    const u32 word = (p & 2u) ? ((o2 << 8) | pair) : ((pair << 8) | o2);

    const u32 s = word >> 15;
    const u32 e = (word >> 10) & 31u;
    const u32 m = word & 1023u;

    // --- normal path: RNE(m >> 7), exponent bump on mantissa carry
    const u32 keep_n   = m >> 7;
    const u32 rbit_n   = (m >> 6) & 1u;
    const u32 sticky_n = (m & 63u) ? 1u : 0u;
    const u32 mant_r   = keep_n + (rbit_n & (sticky_n | (keep_n & 1u)));
    const u32 norm_e   = (e - 8u) + (mant_r >> 3);   // only selected when e >= 9
    const u32 norm_m   = mant_r & 7u;

    // --- subnormal path: RNE((1024 + m) >> clip(16-e, 8, 11))
    u32 k = 16u - e;
    k = k < 8u ? 8u : (k > 11u ? 11u : k);
    const u32 x        = 1024u + m;
    const u32 keep_s   = x >> k;
    const u32 rbit_s   = (x >> (k - 1u)) & 1u;
    const u32 sticky_s = (x & ((1u << (k - 1u)) - 1u)) ? 1u : 0u;
    const u32 m_sub    = keep_s + (rbit_s & (sticky_s | (keep_s & 1u)));
    const u32 sub_e    = m_sub >> 3;
    const u32 sub_m    = (m_sub >= 8u) ? 0u : m_sub;

    // --- branchless select (ovf | unf | subnormal | normal)
    const u32 out_e = (e > 22u) ? 15u : (e < 5u) ? 0u : (e <= 8u) ? sub_e : norm_e;
    const u32 out_m = (e > 22u) ? 6u  : (e < 5u) ? 0u : (e <= 8u) ? sub_m : norm_m;

    // output byte, MSB first: [S, e3, e2, e1, e0, m2, m1, m0]
    const u32 obyte = (s << 7) | (out_e << 3) | out_m;

    // lane p stores output bits (7-2p) and (6-2p) as two pulse words
    const u32 hi = (obyte >> (7u - 2u * p)) & 1u;
    const u32 lo = (obyte >> (6u - 2u * p)) & 1u;

    u32x2 o;
    o.x = (0u - hi) & 0x3F800000u;
    o.y = (0u - lo) & 0x3F800000u;
    out[g] = o;
}

extern "C" void kernel_launch(void* const* d_in, const int* in_sizes, int n_in,
                              void* d_out, int out_size, void* d_ws, size_t ws_size,
                              hipStream_t stream) {
    const u32x4* in = (const u32x4*)d_in[0];
    u32x2* out = (u32x2*)d_out;

    const int n4 = in_sizes[0] / 4;                // 67,108,864 uint4s
    const int block = 256;
    const int grid = (n4 + block - 1) / block;     // 262,144 blocks

    fp16_to_fp8_pulse_kernel<<<grid, block, 0, stream>>>(in, out, n4);
}